// Round 1
// baseline (2817.899 us; speedup 1.0000x reference)
//
#include <hip/hip_runtime.h>

#define T_STEPS 200
#define BATCH   32
#define HID     1024
#define NWG     256
#define NTHR    512

typedef _Float16 half8 __attribute__((ext_vector_type(8)));
typedef float    f32x4 __attribute__((ext_vector_type(4)));

struct Bar {
    unsigned cnt[8 * 32];   // one counter per 128B line per group of 32 WGs
    unsigned gcnt;
    unsigned pad[31];
    unsigned gen;
};

__global__ void init_k(const float* __restrict__ h0,
                       _Float16* __restrict__ h0b, _Float16* __restrict__ h1b,
                       Bar* __restrict__ bar) {
    int i = blockIdx.x * blockDim.x + threadIdx.x;
    if (i < BATCH * HID) {
        h0b[i] = (_Float16)h0[i];                 // layer 0 initial h -> buf 0
        h1b[i] = (_Float16)h0[BATCH * HID + i];   // layer 1 initial h -> buf 0
    }
    if (i == 0) {
        for (int g = 0; g < 8; ++g) bar->cnt[g * 32] = 0;
        bar->gcnt = 0;
        bar->gen  = 0;
    }
}

// 256 WGs x 512 threads. WGs 0-127: layer 0 (step t = tick). WGs 128-255: layer 1
// (step t = tick-1, wavefront pipeline). Each WG owns 8 hidden columns: its 32
// gate-rows of [W_ih ; W_hh] (K=2048) live in LDS (f16, XOR-swizzled) for the
// whole kernel. Per tick: gates = [x_t | h_{t-1}] @ Wslice^T via 16x16x32 f16
// MFMA (8 waves split K 4-ways x M 2-ways), cross-wave reduce in LDS,
// activations on 256 threads (c-state persistent in LDS f32), write h (f16,
// ping-pong), y0*mask_inter (f16) or y*mask_out (f32 out), then grid barrier.
__global__ __launch_bounds__(NTHR, 2) void lstm_main(
    const float* __restrict__ x, const float* __restrict__ c0,
    const float* __restrict__ Wih, const float* __restrict__ Whh,
    const float* __restrict__ bih, const float* __restrict__ bhh,
    const float* __restrict__ mi, const float* __restrict__ mo,
    float* __restrict__ out,
    _Float16* __restrict__ y0m, _Float16* __restrict__ h0b,
    _Float16* __restrict__ h1b, Bar* __restrict__ bar)
{
    __shared__ _Float16 W_s[32 * 2048];     // 128 KB
    __shared__ float scr[8][2][16][17];     // per-wave partial gate tiles (+pad)
    __shared__ float c_s[BATCH][8];         // persistent cell state (f32)

    const int bid   = blockIdx.x;
    const int layer = bid >> 7;
    const int wgl   = bid & 127;
    const int tid   = threadIdx.x;

    // ---- one-time: stage this WG's weight slice into LDS (f16, swizzled) ----
    const float* WihL = Wih + (size_t)layer * 4 * HID * HID;
    const float* WhhL = Whh + (size_t)layer * 4 * HID * HID;
    for (int idx = tid; idx < 32 * 2048; idx += NTHR) {
        int r = idx >> 11, k = idx & 2047;             // r: local gate-row, k: 0..2047
        int grow = (r >> 3) * HID + wgl * 8 + (r & 7); // global row in [4H]
        float v = (k < HID) ? WihL[(size_t)grow * HID + k]
                            : WhhL[(size_t)grow * HID + (k - HID)];
        W_s[idx ^ ((r & 7) << 3)] = (_Float16)v;       // XOR-swizzle (16B granules)
    }

    float bias0 = 0.f, bias1 = 0.f, bias2 = 0.f, bias3 = 0.f;
    int b_ = 0, col_ = 0, gcol = 0;
    if (tid < 256) {
        b_ = tid >> 3; col_ = tid & 7; gcol = wgl * 8 + col_;
        bias0 = bih[layer * 4096 + gcol]           + bhh[layer * 4096 + gcol];
        bias1 = bih[layer * 4096 + HID + gcol]     + bhh[layer * 4096 + HID + gcol];
        bias2 = bih[layer * 4096 + 2 * HID + gcol] + bhh[layer * 4096 + 2 * HID + gcol];
        bias3 = bih[layer * 4096 + 3 * HID + gcol] + bhh[layer * 4096 + 3 * HID + gcol];
        c_s[b_][col_] = c0[((size_t)layer * BATCH + b_) * HID + gcol];
    }
    __syncthreads();

    const int lane = tid & 63, wid = tid >> 6;
    const int m  = wid & 1;          // M-tile (batch 0-15 / 16-31)
    const int kq = wid >> 1;         // K quarter (512 each)
    const int row = lane & 15, bb = m * 16 + row, ko = (lane >> 4) * 8;
    const int grp = bid & 7;

    for (int tk = 0; tk <= T_STEPS; ++tk) {
        const bool active = (layer == 0) ? (tk < T_STEPS) : (tk >= 1);
        if (active) {
            const int t = (layer == 0) ? tk : tk - 1;
            const _Float16* hrd = (layer == 0) ? (h0b + (tk & 1) * (BATCH * HID))
                                               : (h1b + (((tk + 1) & 1)) * (BATCH * HID));
            f32x4 acc0 = {0.f, 0.f, 0.f, 0.f}, acc1 = {0.f, 0.f, 0.f, 0.f};

            // ---- A fragments: [x_t | h] row bb, K quarter kq ----
            half8 aF[16];
            if (kq < 2) {
                if (layer == 0) {
                    const float* xp = x + ((size_t)t * BATCH + bb) * HID + kq * 512 + ko;
                    #pragma unroll
                    for (int kk = 0; kk < 16; ++kk) {
                        f32x4 lo = *(const f32x4*)(xp + kk * 32);
                        f32x4 hi = *(const f32x4*)(xp + kk * 32 + 4);
                        half8 a;
                        a[0] = (_Float16)lo[0]; a[1] = (_Float16)lo[1];
                        a[2] = (_Float16)lo[2]; a[3] = (_Float16)lo[3];
                        a[4] = (_Float16)hi[0]; a[5] = (_Float16)hi[1];
                        a[6] = (_Float16)hi[2]; a[7] = (_Float16)hi[3];
                        aF[kk] = a;
                    }
                } else {
                    const _Float16* yp = y0m + ((size_t)t * BATCH + bb) * HID + kq * 512 + ko;
                    #pragma unroll
                    for (int kk = 0; kk < 16; ++kk) aF[kk] = *(const half8*)(yp + kk * 32);
                }
            } else {
                const _Float16* hp = hrd + bb * HID + (kq - 2) * 512 + ko;
                #pragma unroll
                for (int kk = 0; kk < 16; ++kk) aF[kk] = *(const half8*)(hp + kk * 32);
            }

            // ---- MFMA: D[batch 16][gaterow 16] x2 subtiles over K=512 ----
            #pragma unroll
            for (int kk = 0; kk < 16; ++kk) {
                const int k  = kq * 512 + kk * 32 + ko;
                const int r1 = 16 + row;
                const half8 b0 = *(const half8*)&W_s[(row * 2048 + k) ^ ((row & 7) << 3)];
                const half8 b1 = *(const half8*)&W_s[(r1 * 2048 + k) ^ ((r1 & 7) << 3)];
                acc0 = __builtin_amdgcn_mfma_f32_16x16x32_f16(aF[kk], b0, acc0, 0, 0, 0);
                acc1 = __builtin_amdgcn_mfma_f32_16x16x32_f16(aF[kk], b1, acc1, 0, 0, 0);
            }
            #pragma unroll
            for (int j = 0; j < 4; ++j) {
                scr[wid][0][(lane >> 4) * 4 + j][row] = acc0[j];
                scr[wid][1][(lane >> 4) * 4 + j][row] = acc1[j];
            }
            __syncthreads();

            // ---- activations: thread owns (batch b_, hidden col gcol) ----
            if (tid < 256) {
                const int m2 = b_ >> 4, rD = b_ & 15;
                float v0 = 0.f, v1 = 0.f, v2 = 0.f, v3 = 0.f;
                #pragma unroll
                for (int q = 0; q < 4; ++q) {
                    v0 += scr[q * 2 + m2][0][rD][col_];       // gate i
                    v1 += scr[q * 2 + m2][0][rD][8 + col_];   // gate f
                    v2 += scr[q * 2 + m2][1][rD][col_];       // gate g
                    v3 += scr[q * 2 + m2][1][rD][8 + col_];   // gate o
                }
                const float ig = 1.f / (1.f + __expf(-(v0 + bias0)));
                const float fg = 1.f / (1.f + __expf(-(v1 + bias1)));
                const float gg = tanhf(v2 + bias2);
                const float og = 1.f / (1.f + __expf(-(v3 + bias3)));
                const float cc = fg * c_s[b_][col_] + ig * gg;
                const float hh = og * tanhf(cc);
                c_s[b_][col_] = cc;

                _Float16* hwr = (layer == 0) ? (h0b + (((tk + 1) & 1)) * (BATCH * HID))
                                             : (h1b + ((tk & 1)) * (BATCH * HID));
                hwr[b_ * HID + gcol] = (_Float16)hh;

                const size_t oidx = ((size_t)t * BATCH + b_) * HID + gcol;
                if (layer == 0) {
                    y0m[oidx] = (_Float16)(hh * mi[oidx]);
                } else {
                    out[oidx] = hh * mo[oidx];
                }
                if (t == T_STEPS - 1) {
                    const size_t base = (size_t)T_STEPS * BATCH * HID;
                    out[base + ((size_t)layer * BATCH + b_) * HID + gcol] = hh;
                    out[base + (size_t)2 * BATCH * HID + ((size_t)layer * BATCH + b_) * HID + gcol] = cc;
                }
            }
        }

        // ---- two-level grid barrier ----
        __syncthreads();
        if (tid == 0) {
            const unsigned tgt = (unsigned)(tk + 1);
            __builtin_amdgcn_fence(__ATOMIC_RELEASE, "agent");
            bool fin = false;
            unsigned old = __hip_atomic_fetch_add(&bar->cnt[grp * 32], 1u,
                                                  __ATOMIC_RELAXED, __HIP_MEMORY_SCOPE_AGENT);
            if (old == 31u) {
                unsigned o2 = __hip_atomic_fetch_add(&bar->gcnt, 1u,
                                                     __ATOMIC_RELAXED, __HIP_MEMORY_SCOPE_AGENT);
                if (o2 == 7u) {
                    for (int g = 0; g < 8; ++g)
                        __hip_atomic_store(&bar->cnt[g * 32], 0u,
                                           __ATOMIC_RELAXED, __HIP_MEMORY_SCOPE_AGENT);
                    __hip_atomic_store(&bar->gcnt, 0u,
                                       __ATOMIC_RELAXED, __HIP_MEMORY_SCOPE_AGENT);
                    __builtin_amdgcn_fence(__ATOMIC_RELEASE, "agent");
                    __hip_atomic_store(&bar->gen, tgt,
                                       __ATOMIC_RELEASE, __HIP_MEMORY_SCOPE_AGENT);
                    fin = true;
                }
            }
            if (!fin) {
                while (__hip_atomic_load(&bar->gen, __ATOMIC_RELAXED,
                                         __HIP_MEMORY_SCOPE_AGENT) < tgt)
                    __builtin_amdgcn_s_sleep(2);
            }
            __builtin_amdgcn_fence(__ATOMIC_ACQUIRE, "agent");
        }
        __syncthreads();
    }
}

extern "C" void kernel_launch(void* const* d_in, const int* in_sizes, int n_in,
                              void* d_out, int out_size, void* d_ws, size_t ws_size,
                              hipStream_t stream) {
    const float* x   = (const float*)d_in[0];
    const float* h0  = (const float*)d_in[1];
    const float* c0  = (const float*)d_in[2];
    const float* Wih = (const float*)d_in[3];
    const float* Whh = (const float*)d_in[4];
    const float* bih = (const float*)d_in[5];
    const float* bhh = (const float*)d_in[6];
    const float* mi  = (const float*)d_in[7];
    const float* mo  = (const float*)d_in[8];
    float* out = (float*)d_out;

    char* w = (char*)d_ws;
    _Float16* y0m = (_Float16*)w;                                  // 13,107,200 B
    _Float16* h0b = (_Float16*)(w + 13107200);                     //   131,072 B (2 bufs)
    _Float16* h1b = (_Float16*)(w + 13107200 + 131072);            //   131,072 B
    Bar*      bar = (Bar*)(w + 13107200 + 262144);

    hipLaunchKernelGGL(init_k, dim3(128), dim3(256), 0, stream, h0, h0b, h1b, bar);

    void* args[] = {(void*)&x, (void*)&c0, (void*)&Wih, (void*)&Whh,
                    (void*)&bih, (void*)&bhh, (void*)&mi, (void*)&mo,
                    (void*)&out, (void*)&y0m, (void*)&h0b, (void*)&h1b, (void*)&bar};
    hipLaunchCooperativeKernel((void*)lstm_main, dim3(NWG), dim3(NTHR),
                               args, 0, stream);
}

// Round 2
// 2248.189 us; speedup vs baseline: 1.2534x; 1.2534x over previous
//
#include <hip/hip_runtime.h>

#define T_STEPS 200
#define BATCH   32
#define HID     1024
#define NWG     256
#define NTHR    512

typedef _Float16 half8 __attribute__((ext_vector_type(8)));
typedef float    f32x4 __attribute__((ext_vector_type(4)));

struct Bar {
    unsigned cnt[8 * 32];   // one counter per 128B line per group of 32 WGs
    unsigned gcnt;
    unsigned pad[31];
    unsigned gen;
};

// Coherent (agent-scope, L1/L2-bypassing) 16B load/store built from two
// relaxed 8B atomics. Used ONLY for cross-WG data (h buffers, y0m); no fences
// anywhere -> no buffer_inv / buffer_wbl2 L2 nukes.
__device__ __forceinline__ half8 ld_coh16(const _Float16* p) {
    union { unsigned long long u[2]; half8 h; } r;
    const unsigned long long* q = (const unsigned long long*)p;
    r.u[0] = __hip_atomic_load(q,     __ATOMIC_RELAXED, __HIP_MEMORY_SCOPE_AGENT);
    r.u[1] = __hip_atomic_load(q + 1, __ATOMIC_RELAXED, __HIP_MEMORY_SCOPE_AGENT);
    return r.h;
}
__device__ __forceinline__ void st_coh16(_Float16* p, half8 v) {
    union { half8 h; unsigned long long u[2]; } r; r.h = v;
    unsigned long long* q = (unsigned long long*)p;
    __hip_atomic_store(q,     r.u[0], __ATOMIC_RELAXED, __HIP_MEMORY_SCOPE_AGENT);
    __hip_atomic_store(q + 1, r.u[1], __ATOMIC_RELAXED, __HIP_MEMORY_SCOPE_AGENT);
}

__global__ void init_k(const float* __restrict__ h0,
                       _Float16* __restrict__ h0b, _Float16* __restrict__ h1b,
                       Bar* __restrict__ bar) {
    int i = blockIdx.x * blockDim.x + threadIdx.x;
    if (i < BATCH * HID) {
        h0b[i] = (_Float16)h0[i];                 // layer 0 initial h -> buf 0
        h1b[i] = (_Float16)h0[BATCH * HID + i];   // layer 1 initial h -> buf 0
    }
    if (i == 0) {
        for (int g = 0; g < 8; ++g) bar->cnt[g * 32] = 0;
        bar->gcnt = 0;
        bar->gen  = 0;
    }
}

// 256 WGs x 512 threads. WGs 0-127: layer 0 (step t = tick). WGs 128-255:
// layer 1 (step t = tick-1, wavefront pipeline). Weights live in LDS (f16,
// XOR-swizzled) for the whole kernel. Cross-WG traffic (h ping-pong, y0m)
// goes through relaxed agent-scope atomics (always at LLC); everything else
// stays normally cached. Grid barrier is fence-free: ordering via
// s_waitcnt vmcnt(0) on wave 0 (which issues all communicated stores).
__global__ __launch_bounds__(NTHR, 2) void lstm_main(
    const float* __restrict__ x, const float* __restrict__ c0,
    const float* __restrict__ Wih, const float* __restrict__ Whh,
    const float* __restrict__ bih, const float* __restrict__ bhh,
    const float* __restrict__ mi, const float* __restrict__ mo,
    float* __restrict__ out,
    _Float16* __restrict__ y0m, _Float16* __restrict__ h0b,
    _Float16* __restrict__ h1b, Bar* __restrict__ bar)
{
    __shared__ _Float16 W_s[32 * 2048];     // 128 KB
    __shared__ float scr[8][2][16][17];     // per-wave partial gate tiles (+pad)
    __shared__ float c_s[BATCH][8];         // persistent cell state (f32)
    __shared__ alignas(16) _Float16 st_h[BATCH][8];  // staged h for wave-0 stores
    __shared__ alignas(16) _Float16 st_y[BATCH][8];  // staged y0*mask (layer 0)

    const int bid   = blockIdx.x;
    const int layer = bid >> 7;
    const int wgl   = bid & 127;
    const int tid   = threadIdx.x;

    // ---- one-time: stage this WG's weight slice into LDS (f16, swizzled) ----
    const float* WihL = Wih + (size_t)layer * 4 * HID * HID;
    const float* WhhL = Whh + (size_t)layer * 4 * HID * HID;
    for (int idx = tid; idx < 32 * 2048; idx += NTHR) {
        int r = idx >> 11, k = idx & 2047;             // r: local gate-row, k: 0..2047
        int grow = (r >> 3) * HID + wgl * 8 + (r & 7); // global row in [4H]
        float v = (k < HID) ? WihL[(size_t)grow * HID + k]
                            : WhhL[(size_t)grow * HID + (k - HID)];
        W_s[idx ^ ((r & 7) << 3)] = (_Float16)v;       // XOR-swizzle (16B granules)
    }

    float bias0 = 0.f, bias1 = 0.f, bias2 = 0.f, bias3 = 0.f;
    int b_ = 0, col_ = 0, gcol = 0;
    if (tid < 256) {
        b_ = tid >> 3; col_ = tid & 7; gcol = wgl * 8 + col_;
        bias0 = bih[layer * 4096 + gcol]           + bhh[layer * 4096 + gcol];
        bias1 = bih[layer * 4096 + HID + gcol]     + bhh[layer * 4096 + HID + gcol];
        bias2 = bih[layer * 4096 + 2 * HID + gcol] + bhh[layer * 4096 + 2 * HID + gcol];
        bias3 = bih[layer * 4096 + 3 * HID + gcol] + bhh[layer * 4096 + 3 * HID + gcol];
        c_s[b_][col_] = c0[((size_t)layer * BATCH + b_) * HID + gcol];
    }
    __syncthreads();

    const int lane = tid & 63, wid = tid >> 6;
    const int m  = wid & 1;          // M-tile (batch 0-15 / 16-31)
    const int kq = wid >> 1;         // K quarter (512 each)
    const int row = lane & 15, bb = m * 16 + row, ko = (lane >> 4) * 8;
    const int grp = bid & 7;

    for (int tk = 0; tk <= T_STEPS; ++tk) {
        const bool active = (layer == 0) ? (tk < T_STEPS) : (tk >= 1);
        if (active) {
            const int t = (layer == 0) ? tk : tk - 1;
            const _Float16* hrd = (layer == 0) ? (h0b + (tk & 1) * (BATCH * HID))
                                               : (h1b + (((tk + 1) & 1)) * (BATCH * HID));
            f32x4 acc0 = {0.f, 0.f, 0.f, 0.f}, acc1 = {0.f, 0.f, 0.f, 0.f};

            // ---- A fragments: [x_t | h] row bb, K quarter kq ----
            half8 aF[16];
            if (kq < 2) {
                if (layer == 0) {
                    const float* xp = x + ((size_t)t * BATCH + bb) * HID + kq * 512 + ko;
                    #pragma unroll
                    for (int kk = 0; kk < 16; ++kk) {
                        f32x4 lo = *(const f32x4*)(xp + kk * 32);
                        f32x4 hi = *(const f32x4*)(xp + kk * 32 + 4);
                        half8 a;
                        a[0] = (_Float16)lo[0]; a[1] = (_Float16)lo[1];
                        a[2] = (_Float16)lo[2]; a[3] = (_Float16)lo[3];
                        a[4] = (_Float16)hi[0]; a[5] = (_Float16)hi[1];
                        a[6] = (_Float16)hi[2]; a[7] = (_Float16)hi[3];
                        aF[kk] = a;
                    }
                } else {
                    const _Float16* yp = y0m + ((size_t)t * BATCH + bb) * HID + kq * 512 + ko;
                    #pragma unroll
                    for (int kk = 0; kk < 16; ++kk) aF[kk] = ld_coh16(yp + kk * 32);
                }
            } else {
                const _Float16* hp = hrd + bb * HID + (kq - 2) * 512 + ko;
                #pragma unroll
                for (int kk = 0; kk < 16; ++kk) aF[kk] = ld_coh16(hp + kk * 32);
            }

            // ---- MFMA: D[batch 16][gaterow 16] x2 subtiles over K=512 ----
            #pragma unroll
            for (int kk = 0; kk < 16; ++kk) {
                const int k  = kq * 512 + kk * 32 + ko;
                const int r1 = 16 + row;
                const half8 b0 = *(const half8*)&W_s[(row * 2048 + k) ^ ((row & 7) << 3)];
                const half8 b1 = *(const half8*)&W_s[(r1 * 2048 + k) ^ ((r1 & 7) << 3)];
                acc0 = __builtin_amdgcn_mfma_f32_16x16x32_f16(aF[kk], b0, acc0, 0, 0, 0);
                acc1 = __builtin_amdgcn_mfma_f32_16x16x32_f16(aF[kk], b1, acc1, 0, 0, 0);
            }
            #pragma unroll
            for (int j = 0; j < 4; ++j) {
                scr[wid][0][(lane >> 4) * 4 + j][row] = acc0[j];
                scr[wid][1][(lane >> 4) * 4 + j][row] = acc1[j];
            }
            __syncthreads();

            // ---- activations: thread owns (batch b_, hidden col gcol) ----
            if (tid < 256) {
                const int m2 = b_ >> 4, rD = b_ & 15;
                float v0 = 0.f, v1 = 0.f, v2 = 0.f, v3 = 0.f;
                #pragma unroll
                for (int q = 0; q < 4; ++q) {
                    v0 += scr[q * 2 + m2][0][rD][col_];       // gate i
                    v1 += scr[q * 2 + m2][0][rD][8 + col_];   // gate f
                    v2 += scr[q * 2 + m2][1][rD][col_];       // gate g
                    v3 += scr[q * 2 + m2][1][rD][8 + col_];   // gate o
                }
                const float ig = 1.f / (1.f + __expf(-(v0 + bias0)));
                const float fg = 1.f / (1.f + __expf(-(v1 + bias1)));
                const float gg = tanhf(v2 + bias2);
                const float og = 1.f / (1.f + __expf(-(v3 + bias3)));
                const float cc = fg * c_s[b_][col_] + ig * gg;
                const float hh = og * tanhf(cc);
                c_s[b_][col_] = cc;

                st_h[b_][col_] = (_Float16)hh;

                const size_t oidx = ((size_t)t * BATCH + b_) * HID + gcol;
                if (layer == 0) {
                    st_y[b_][col_] = (_Float16)(hh * mi[oidx]);
                } else {
                    out[oidx] = hh * mo[oidx];
                }
                if (t == T_STEPS - 1) {
                    const size_t base = (size_t)T_STEPS * BATCH * HID;
                    out[base + ((size_t)layer * BATCH + b_) * HID + gcol] = hh;
                    out[base + (size_t)2 * BATCH * HID + ((size_t)layer * BATCH + b_) * HID + gcol] = cc;
                }
            }
            __syncthreads();

            // ---- wave 0 funnels ALL cross-WG stores (covered by one vmcnt) ----
            if (tid < BATCH) {
                _Float16* hwr = (layer == 0) ? (h0b + (((tk + 1) & 1)) * (BATCH * HID))
                                             : (h1b + ((tk & 1)) * (BATCH * HID));
                st_coh16(&hwr[tid * HID + wgl * 8], *(const half8*)st_h[tid]);
                if (layer == 0)
                    st_coh16(&y0m[((size_t)t * BATCH + tid) * HID + wgl * 8],
                             *(const half8*)st_y[tid]);
            }
        }

        // ---- fence-free two-level grid barrier ----
        if (tid == 0) {
            // all communicated stores were issued by this wave -> one waitcnt
            asm volatile("s_waitcnt vmcnt(0)" ::: "memory");
            const unsigned tgt = (unsigned)(tk + 1);
            bool fin = false;
            unsigned old = __hip_atomic_fetch_add(&bar->cnt[grp * 32], 1u,
                                                  __ATOMIC_RELAXED, __HIP_MEMORY_SCOPE_AGENT);
            if (old == 31u) {
                unsigned o2 = __hip_atomic_fetch_add(&bar->gcnt, 1u,
                                                     __ATOMIC_RELAXED, __HIP_MEMORY_SCOPE_AGENT);
                if (o2 == 7u) {
                    for (int g = 0; g < 8; ++g)
                        __hip_atomic_store(&bar->cnt[g * 32], 0u,
                                           __ATOMIC_RELAXED, __HIP_MEMORY_SCOPE_AGENT);
                    __hip_atomic_store(&bar->gcnt, 0u,
                                       __ATOMIC_RELAXED, __HIP_MEMORY_SCOPE_AGENT);
                    // resets must hit LLC before gen is published
                    asm volatile("s_waitcnt vmcnt(0)" ::: "memory");
                    __hip_atomic_store(&bar->gen, tgt,
                                       __ATOMIC_RELAXED, __HIP_MEMORY_SCOPE_AGENT);
                    fin = true;
                }
            }
            if (!fin) {
                while (__hip_atomic_load(&bar->gen, __ATOMIC_RELAXED,
                                         __HIP_MEMORY_SCOPE_AGENT) < tgt)
                    __builtin_amdgcn_s_sleep(1);
            }
            asm volatile("" ::: "memory");   // no code motion across the spin
        }
        __syncthreads();
    }
}

extern "C" void kernel_launch(void* const* d_in, const int* in_sizes, int n_in,
                              void* d_out, int out_size, void* d_ws, size_t ws_size,
                              hipStream_t stream) {
    const float* x   = (const float*)d_in[0];
    const float* h0  = (const float*)d_in[1];
    const float* c0  = (const float*)d_in[2];
    const float* Wih = (const float*)d_in[3];
    const float* Whh = (const float*)d_in[4];
    const float* bih = (const float*)d_in[5];
    const float* bhh = (const float*)d_in[6];
    const float* mi  = (const float*)d_in[7];
    const float* mo  = (const float*)d_in[8];
    float* out = (float*)d_out;

    char* w = (char*)d_ws;
    _Float16* y0m = (_Float16*)w;                                  // 13,107,200 B
    _Float16* h0b = (_Float16*)(w + 13107200);                     //   131,072 B (2 bufs)
    _Float16* h1b = (_Float16*)(w + 13107200 + 131072);            //   131,072 B
    Bar*      bar = (Bar*)(w + 13107200 + 262144);

    hipLaunchKernelGGL(init_k, dim3(128), dim3(256), 0, stream, h0, h0b, h1b, bar);

    void* args[] = {(void*)&x, (void*)&c0, (void*)&Wih, (void*)&Whh,
                    (void*)&bih, (void*)&bhh, (void*)&mi, (void*)&mo,
                    (void*)&out, (void*)&y0m, (void*)&h0b, (void*)&h1b, (void*)&bar};
    hipLaunchCooperativeKernel((void*)lstm_main, dim3(NWG), dim3(NTHR),
                               args, 0, stream);
}